// Round 4
// baseline (238.966 us; speedup 1.0000x reference)
//
#include <hip/hip_runtime.h>
#include <hip/hip_bf16.h>

typedef unsigned short ushort_t;
typedef __bf16 bf16x8 __attribute__((ext_vector_type(8)));
typedef float f32x4 __attribute__((ext_vector_type(4)));
typedef ushort_t ushort8_t __attribute__((ext_vector_type(8)));

__device__ __forceinline__ float bf2f(ushort_t u) {
    union { unsigned int i; float f; } x; x.i = ((unsigned int)u) << 16; return x.f;
}
__device__ __forceinline__ ushort_t f2bf(float f) {
    __hip_bfloat16 h = __float2bfloat16(f);
    return *(ushort_t*)&h;
}
__device__ __forceinline__ void async16(const void* g, void* l) {
    __builtin_amdgcn_global_load_lds((const __attribute__((address_space(1))) void*)g,
                                     (__attribute__((address_space(3))) void*)l, 16, 0, 0);
}

// ---- fused prep: blocks [0,8192): x fp32->bf16 (2 float4/thread); [8192,9216): W_in^T*Bv; [9216,10240): C^T ----
__global__ void prep_fused(const float* __restrict__ x, const float* __restrict__ W_in,
                           const float* __restrict__ C, const float* __restrict__ Bv,
                           __hip_bfloat16* __restrict__ xb, __hip_bfloat16* __restrict__ Wpt,
                           __hip_bfloat16* __restrict__ Ct) {
    int bid = blockIdx.x;
    if (bid < 8192) {
        size_t idx = ((size_t)bid * 256 + threadIdx.x) * 8;
        float4 v0 = *(const float4*)(x + idx);
        float4 v1 = *(const float4*)(x + idx + 4);
        ushort8_t ov;
        ov[0] = f2bf(v0.x); ov[1] = f2bf(v0.y); ov[2] = f2bf(v0.z); ov[3] = f2bf(v0.w);
        ov[4] = f2bf(v1.x); ov[5] = f2bf(v1.y); ov[6] = f2bf(v1.z); ov[7] = f2bf(v1.w);
        *(ushort8_t*)((ushort_t*)xb + idx) = ov;
        return;
    }
    __shared__ float tile[32][33];
    const float* in;
    __hip_bfloat16* out;
    bool do_scale;
    int lid;
    if (bid < 9216) { lid = bid - 8192; in = W_in; out = Wpt; do_scale = true; }
    else            { lid = bid - 9216; in = C;    out = Ct;  do_scale = false; }
    int bx = (lid & 31) * 32;   // n base
    int by = (lid >> 5) * 32;   // k base
    int tx = threadIdx.x & 31, ty = threadIdx.x >> 5;  // ty 0..7
    #pragma unroll
    for (int i = 0; i < 32; i += 8)
        tile[ty + i][tx] = in[(size_t)(by + ty + i) * 1024 + bx + tx];
    __syncthreads();
    #pragma unroll
    for (int i = 0; i < 32; i += 8) {
        int n = bx + ty + i;
        int k = by + tx;
        float s = do_scale ? Bv[n] : 1.0f;
        out[(size_t)n * 1024 + k] = __float2bfloat16(tile[tx][ty + i] * s);
    }
}

// ---- 256x256 8-phase GEMM (T2+T3+T4+T5), D = A * Bt^T ----
// M=16384, N=1024, K=1024 fixed. 512 thr = 8 waves (2M x 4N), per-wave C = 128x64.
// Verified round 3: 53.5us, MfmaUtil 23%, 0 bank conflicts. This rev: STAGE issued
// before ds_reads (T3 recipe) + partial lgkmcnt(8) pre-barrier in 12-read phases.
#define CBAR() asm volatile("" ::: "memory")
#define BARX() do { CBAR(); __builtin_amdgcn_s_barrier(); CBAR(); } while (0)
#define WAIT_LGKM0() do { asm volatile("s_waitcnt lgkmcnt(0)" ::: "memory"); \
                          __builtin_amdgcn_sched_barrier(0); } while (0)
#define WAIT_LGKM8() asm volatile("s_waitcnt lgkmcnt(8)" ::: "memory")
#define WAIT_VM0() asm volatile("s_waitcnt vmcnt(0)" ::: "memory")

template <int EPI>
__global__ __launch_bounds__(512) void gemm256(
    const __hip_bfloat16* __restrict__ Ab, const __hip_bfloat16* __restrict__ Btb,
    const float* __restrict__ b_in, const float* __restrict__ Bv,
    __hip_bfloat16* __restrict__ out_bf,
    const __hip_bfloat16* __restrict__ xres_bf, const float* __restrict__ Dvec,
    float* __restrict__ out_f) {
    constexpr int N = 1024, K = 1024;
    constexpr int BK2 = 64;
    const int tid  = threadIdx.x;
    const int wave = tid >> 6;     // 0..7
    const int lane = tid & 63;
    const int quad = lane >> 4;    // 0..3
    const int lr   = lane & 15;
    const int wm   = wave >> 2;    // 0..1
    const int wn   = wave & 3;     // 0..3

    // bijective XCD swizzle: 256 wgs, 32/XCD
    const int lin   = blockIdx.x;
    const int wg    = (lin & 7) * 32 + (lin >> 3);
    const int m0    = (wg >> 2) * 256;
    const int n0    = (wg & 3) * 256;

    __shared__ __align__(16) ushort_t sA[2][256 * BK2];  // 64 KB
    __shared__ __align__(16) ushort_t sB[2][256 * BK2];  // 64 KB

    const ushort_t* A  = (const ushort_t*)Ab;
    const ushort_t* Bt = (const ushort_t*)Btb;

    f32x4 acc[8][4];
    #pragma unroll
    for (int i = 0; i < 8; ++i)
        #pragma unroll
        for (int j = 0; j < 4; ++j)
            #pragma unroll
            for (int r = 0; r < 4; ++r) acc[i][j][r] = 0.0f;

    // staging: wave w covers tile rows [w*32, w*32+32), 4 issues of 8 rows each.
    // lane l -> row +(l>>3), LDS chunk l&7; source logical chunk (l&7)^(l>>3)
    // so LDS[row][pc] holds logical chunk pc^(row&7).
    const int l8  = lane >> 3;
    const int sch = (lane & 7) ^ l8;
    const ushort_t* gA = A  + (size_t)(m0 + wave * 32 + l8) * K + sch * 8;
    const ushort_t* gB = Bt + (size_t)(n0 + wave * 32 + l8) * K + sch * 8;
    const int ldsb = wave * 32 * BK2;

#define STAGE(s, k0) do { \
    _Pragma("unroll") \
    for (int g = 0; g < 4; ++g) { \
        async16(gA + (size_t)g * 8 * K + (k0), &sA[s][ldsb + g * 8 * BK2]); \
        async16(gB + (size_t)g * 8 * K + (k0), &sB[s][ldsb + g * 8 * BK2]); \
    } } while (0)

    // fragment reads: row_a&7 == lr&7, so physical chunk = (ks*4+quad)^(lr&7)
    const int pc0 = ((quad       ^ (lr & 7)) << 3);
    const int pc1 = (((quad + 4) ^ (lr & 7)) << 3);
    const int arow = (wm * 128 + lr) * BK2;
    const int brow = (wn * 64  + lr) * BK2;

    bf16x8 af[4][2], bfr[2][2];
#define LDA(s, mh) do { \
    _Pragma("unroll") for (int i = 0; i < 4; ++i) { \
        af[i][0] = *(const bf16x8*)&sA[s][arow + ((mh) * 64 + i * 16) * BK2 + pc0]; \
        af[i][1] = *(const bf16x8*)&sA[s][arow + ((mh) * 64 + i * 16) * BK2 + pc1]; \
    } } while (0)
#define LDB(s, nh) do { \
    _Pragma("unroll") for (int j = 0; j < 2; ++j) { \
        bfr[j][0] = *(const bf16x8*)&sB[s][brow + ((nh) * 32 + j * 16) * BK2 + pc0]; \
        bfr[j][1] = *(const bf16x8*)&sB[s][brow + ((nh) * 32 + j * 16) * BK2 + pc1]; \
    } } while (0)
#define MFMA16(mh, nh) do { \
    __builtin_amdgcn_s_setprio(1); \
    _Pragma("unroll") for (int i = 0; i < 4; ++i) \
    _Pragma("unroll") for (int j = 0; j < 2; ++j) { \
        acc[(mh)*4+i][(nh)*2+j] = __builtin_amdgcn_mfma_f32_16x16x32_bf16(af[i][0], bfr[j][0], acc[(mh)*4+i][(nh)*2+j], 0, 0, 0); \
        acc[(mh)*4+i][(nh)*2+j] = __builtin_amdgcn_mfma_f32_16x16x32_bf16(af[i][1], bfr[j][1], acc[(mh)*4+i][(nh)*2+j], 0, 0, 0); \
    } \
    __builtin_amdgcn_s_setprio(0); } while (0)

    // prologue: tile 0 -> slot 0 (one-time full drain)
    STAGE(0, 0);
    WAIT_VM0();
    BARX();

    for (int it = 0; it < 8; ++it) {
        const int k1 = it * 128 + 64;    // tile 2it+1
        const int k2 = it * 128 + 128;   // tile 2it+2
        // ph1: stage tile 2it+1 -> slot1 first (loads in flight earliest), then slot0 (0,0)
        STAGE(1, k1);
        LDA(0, 0); LDB(0, 0);
        WAIT_LGKM8();
        BARX(); WAIT_LGKM0();
        MFMA16(0, 0);
        BARX();
        // ph2: (0,1)  [A mh0 cached]
        LDB(0, 1);
        BARX(); WAIT_LGKM0();
        MFMA16(0, 1);
        BARX();
        // ph3: (1,1)  [B nh1 cached]
        LDA(0, 1);
        BARX(); WAIT_LGKM0();
        MFMA16(1, 1);
        BARX();
        // ph4: (1,0)  [A mh1 cached]
        LDB(0, 0);
        BARX(); WAIT_LGKM0();
        MFMA16(1, 0);
        WAIT_VM0();   // tile 2it+1 landed (loads 3 phases old)
        BARX();
        // ph5: stage tile 2it+2 -> slot0 first, then slot1 (0,0)
        if (it < 7) STAGE(0, k2);
        LDA(1, 0); LDB(1, 0);
        WAIT_LGKM8();
        BARX(); WAIT_LGKM0();
        MFMA16(0, 0);
        BARX();
        // ph6: (0,1)
        LDB(1, 1);
        BARX(); WAIT_LGKM0();
        MFMA16(0, 1);
        BARX();
        // ph7: (1,1)
        LDA(1, 1);
        BARX(); WAIT_LGKM0();
        MFMA16(1, 1);
        BARX();
        // ph8: (1,0)
        LDB(1, 0);
        BARX(); WAIT_LGKM0();
        MFMA16(1, 0);
        WAIT_VM0();   // tile 2it+2 landed
        BARX();
    }

    // epilogue: C/D layout col=lane&15, row=quad*4+reg
    #pragma unroll
    for (int mf = 0; mf < 8; ++mf) {
        int row = m0 + wm * 128 + mf * 16 + quad * 4;
        #pragma unroll
        for (int nf = 0; nf < 4; ++nf) {
            int col = n0 + wn * 64 + nf * 16 + lr;
            if constexpr (EPI == 0) {
                float bs = b_in[col] * Bv[col];
                #pragma unroll
                for (int r = 0; r < 4; ++r)
                    out_bf[(size_t)(row + r) * N + col] = __float2bfloat16(acc[mf][nf][r] + bs);
            } else {
                float dv = Dvec[col];
                #pragma unroll
                for (int r = 0; r < 4; ++r) {
                    float xv = bf2f(((const ushort_t*)xres_bf)[(size_t)(row + r) * N + col]);
                    out_f[(size_t)(row + r) * N + col] = acc[mf][nf][r] + xv * dv;
                }
            }
        }
    }
#undef STAGE
#undef LDA
#undef LDB
#undef MFMA16
}

// ---- chunked scan: h_t = a*h_{t-1} + b_t, bf16 in/out ----
// v2: 4 channels/thread via ushort4 (8 B/lane loads, G13) -> grid (T/32, 8),
// 512 blocks, 2/CU, 8 waves/CU. Warm-up exact to fp32 (|a|^32 ~ 1e-14).
#define SCH 32
__global__ void scan_kernel(const __hip_bfloat16* __restrict__ b, __hip_bfloat16* __restrict__ h,
                            const float* __restrict__ logA, int T, int DD) {
    int c0 = threadIdx.x * 4;          // 4 channels per thread
    int q  = blockIdx.x;               // chunk index
    int bb = blockIdx.y;               // batch
    float4 la = *(const float4*)(logA + c0);
    float a1c[4], a2c[4], a3c[4], a4c[4];
    a1c[0] = -__expf(la.x); a1c[1] = -__expf(la.y);
    a1c[2] = -__expf(la.z); a1c[3] = -__expf(la.w);
    #pragma unroll
    for (int c = 0; c < 4; ++c) {
        a2c[c] = a1c[c] * a1c[c];
        a3c[c] = a2c[c] * a1c[c];
        a4c[c] = a2c[c] * a2c[c];
    }
    int ts = q * SCH;
    size_t base = (size_t)bb * T * DD + c0;
    float hh[4] = {0.f, 0.f, 0.f, 0.f};
    if (ts > 0) {
        const ushort_t* wp = (const ushort_t*)b + base + (size_t)(ts - 32) * DD;
        #pragma unroll
        for (int t = 0; t < 32; t += 4) {
            ushort4 v0 = *(const ushort4*)(wp);
            ushort4 v1 = *(const ushort4*)(wp + DD);
            ushort4 v2 = *(const ushort4*)(wp + 2 * (size_t)DD);
            ushort4 v3 = *(const ushort4*)(wp + 3 * (size_t)DD);
            wp += 4 * (size_t)DD;
            const ushort_t* p0 = (const ushort_t*)&v0;
            const ushort_t* p1 = (const ushort_t*)&v1;
            const ushort_t* p2 = (const ushort_t*)&v2;
            const ushort_t* p3 = (const ushort_t*)&v3;
            #pragma unroll
            for (int c = 0; c < 4; ++c) {
                float s = fmaf(a3c[c], bf2f(p0[c]), fmaf(a2c[c], bf2f(p1[c]),
                          fmaf(a1c[c], bf2f(p2[c]), bf2f(p3[c]))));
                hh[c] = fmaf(a4c[c], hh[c], s);
            }
        }
    }
    const ushort_t* bp = (const ushort_t*)b + base + (size_t)ts * DD;
    ushort_t* hp = (ushort_t*)h + base + (size_t)ts * DD;
    #pragma unroll
    for (int t = 0; t < SCH; t += 4) {
        ushort4 v0 = *(const ushort4*)(bp);
        ushort4 v1 = *(const ushort4*)(bp + DD);
        ushort4 v2 = *(const ushort4*)(bp + 2 * (size_t)DD);
        ushort4 v3 = *(const ushort4*)(bp + 3 * (size_t)DD);
        bp += 4 * (size_t)DD;
        const ushort_t* p0 = (const ushort_t*)&v0;
        const ushort_t* p1 = (const ushort_t*)&v1;
        const ushort_t* p2 = (const ushort_t*)&v2;
        const ushort_t* p3 = (const ushort_t*)&v3;
        ushort4 o0, o1, o2, o3;
        ushort_t* q0 = (ushort_t*)&o0; ushort_t* q1 = (ushort_t*)&o1;
        ushort_t* q2 = (ushort_t*)&o2; ushort_t* q3 = (ushort_t*)&o3;
        #pragma unroll
        for (int c = 0; c < 4; ++c) {
            hh[c] = fmaf(a1c[c], hh[c], bf2f(p0[c])); q0[c] = f2bf(hh[c]);
            hh[c] = fmaf(a1c[c], hh[c], bf2f(p1[c])); q1[c] = f2bf(hh[c]);
            hh[c] = fmaf(a1c[c], hh[c], bf2f(p2[c])); q2[c] = f2bf(hh[c]);
            hh[c] = fmaf(a1c[c], hh[c], bf2f(p3[c])); q3[c] = f2bf(hh[c]);
        }
        *(ushort4*)hp = o0;
        *(ushort4*)(hp + DD) = o1;
        *(ushort4*)(hp + 2 * (size_t)DD) = o2;
        *(ushort4*)(hp + 3 * (size_t)DD) = o3;
        hp += 4 * (size_t)DD;
    }
}

extern "C" void kernel_launch(void* const* d_in, const int* in_sizes, int n_in,
                              void* d_out, int out_size, void* d_ws, size_t ws_size,
                              hipStream_t stream) {
    const float* x    = (const float*)d_in[0];
    const float* W_in = (const float*)d_in[1];
    const float* b_in = (const float*)d_in[2];
    const float* logA = (const float*)d_in[3];
    const float* Bv   = (const float*)d_in[4];
    const float* C    = (const float*)d_in[5];
    const float* Dv   = (const float*)d_in[6];
    float* out = (float*)d_out;

    const int Bsz = 8, T = 2048, d = 1024;
    const int M = Bsz * T;  // 16384

    // workspace carve (~100 MB)
    char* w = (char*)d_ws;
    __hip_bfloat16* xb   = (__hip_bfloat16*)w;                 // 32 MB
    __hip_bfloat16* Wpt  = xb + (size_t)M * d;                 //  2 MB
    __hip_bfloat16* Ct   = Wpt + (size_t)d * d;                //  2 MB
    __hip_bfloat16* bbuf = Ct + (size_t)d * d;                 // 32 MB
    __hip_bfloat16* hbuf = bbuf + (size_t)M * d;               // 32 MB

    prep_fused<<<8192 + 2048, 256, 0, stream>>>(x, W_in, C, Bv, xb, Wpt, Ct);

    gemm256<0><<<256, 512, 0, stream>>>(xb, Wpt, b_in, Bv, bbuf, nullptr, nullptr, nullptr);
    scan_kernel<<<dim3(T / SCH, Bsz), 256, 0, stream>>>(bbuf, hbuf, logA, T, d);
    gemm256<1><<<256, 512, 0, stream>>>(hbuf, Ct, nullptr, nullptr, nullptr, xb, Dv, out);
}

// Round 5
// 234.301 us; speedup vs baseline: 1.0199x; 1.0199x over previous
//
#include <hip/hip_runtime.h>
#include <hip/hip_bf16.h>

typedef unsigned short ushort_t;
typedef __bf16 bf16x8 __attribute__((ext_vector_type(8)));
typedef float f32x4 __attribute__((ext_vector_type(4)));
typedef ushort_t ushort8_t __attribute__((ext_vector_type(8)));

__device__ __forceinline__ float bf2f(ushort_t u) {
    union { unsigned int i; float f; } x; x.i = ((unsigned int)u) << 16; return x.f;
}
__device__ __forceinline__ ushort_t f2bf(float f) {
    __hip_bfloat16 h = __float2bfloat16(f);
    return *(ushort_t*)&h;
}
__device__ __forceinline__ void async16(const void* g, void* l) {
    __builtin_amdgcn_global_load_lds((const __attribute__((address_space(1))) void*)g,
                                     (__attribute__((address_space(3))) void*)l, 16, 0, 0);
}

// ---- fused prep: blocks [0,8192): x fp32->bf16 (2 float4/thread); [8192,9216): W_in^T*Bv; [9216,10240): C^T ----
__global__ void prep_fused(const float* __restrict__ x, const float* __restrict__ W_in,
                           const float* __restrict__ C, const float* __restrict__ Bv,
                           __hip_bfloat16* __restrict__ xb, __hip_bfloat16* __restrict__ Wpt,
                           __hip_bfloat16* __restrict__ Ct) {
    int bid = blockIdx.x;
    if (bid < 8192) {
        size_t idx = ((size_t)bid * 256 + threadIdx.x) * 8;
        float4 v0 = *(const float4*)(x + idx);
        float4 v1 = *(const float4*)(x + idx + 4);
        ushort8_t ov;
        ov[0] = f2bf(v0.x); ov[1] = f2bf(v0.y); ov[2] = f2bf(v0.z); ov[3] = f2bf(v0.w);
        ov[4] = f2bf(v1.x); ov[5] = f2bf(v1.y); ov[6] = f2bf(v1.z); ov[7] = f2bf(v1.w);
        *(ushort8_t*)((ushort_t*)xb + idx) = ov;
        return;
    }
    __shared__ float tile[32][33];
    const float* in;
    __hip_bfloat16* out;
    bool do_scale;
    int lid;
    if (bid < 9216) { lid = bid - 8192; in = W_in; out = Wpt; do_scale = true; }
    else            { lid = bid - 9216; in = C;    out = Ct;  do_scale = false; }
    int bx = (lid & 31) * 32;   // n base
    int by = (lid >> 5) * 32;   // k base
    int tx = threadIdx.x & 31, ty = threadIdx.x >> 5;  // ty 0..7
    #pragma unroll
    for (int i = 0; i < 32; i += 8)
        tile[ty + i][tx] = in[(size_t)(by + ty + i) * 1024 + bx + tx];
    __syncthreads();
    #pragma unroll
    for (int i = 0; i < 32; i += 8) {
        int n = bx + ty + i;
        int k = by + tx;
        float s = do_scale ? Bv[n] : 1.0f;
        out[(size_t)n * 1024 + k] = __float2bfloat16(tile[tx][ty + i] * s);
    }
}

// ---- 256x256 8-phase GEMM (T2+T3+T4+T5), D = A * Bt^T ----
// M=16384, N=1024, K=1024 fixed. 512 thr = 8 waves (2M x 4N), per-wave C = 128x64.
// EXACT round-3 schedule (verified 53.5us, MfmaUtil 23%, 0 bank conflicts).
// Round-4 lesson: do NOT issue STAGE before the ds_reads and do NOT add a counted
// lgkmcnt after a STAGE burst — global_load_lds is FLAT-encoded (increments vmcnt
// AND lgkmcnt), so lgkmcnt(8) there gates on HBM-latency stage loads: +19us/GEMM.
#define CBAR() asm volatile("" ::: "memory")
#define BARX() do { CBAR(); __builtin_amdgcn_s_barrier(); CBAR(); } while (0)
#define WAIT_LGKM0() do { asm volatile("s_waitcnt lgkmcnt(0)" ::: "memory"); \
                          __builtin_amdgcn_sched_barrier(0); } while (0)
#define WAIT_VM0() asm volatile("s_waitcnt vmcnt(0)" ::: "memory")

template <int EPI>
__global__ __launch_bounds__(512) void gemm256(
    const __hip_bfloat16* __restrict__ Ab, const __hip_bfloat16* __restrict__ Btb,
    const float* __restrict__ b_in, const float* __restrict__ Bv,
    __hip_bfloat16* __restrict__ out_bf,
    const __hip_bfloat16* __restrict__ xres_bf, const float* __restrict__ Dvec,
    float* __restrict__ out_f) {
    constexpr int N = 1024, K = 1024;
    constexpr int BK2 = 64;
    const int tid  = threadIdx.x;
    const int wave = tid >> 6;     // 0..7
    const int lane = tid & 63;
    const int quad = lane >> 4;    // 0..3
    const int lr   = lane & 15;
    const int wm   = wave >> 2;    // 0..1
    const int wn   = wave & 3;     // 0..3

    // bijective XCD swizzle: 256 wgs, 32/XCD
    const int lin   = blockIdx.x;
    const int wg    = (lin & 7) * 32 + (lin >> 3);
    const int m0    = (wg >> 2) * 256;
    const int n0    = (wg & 3) * 256;

    __shared__ __align__(16) ushort_t sA[2][256 * BK2];  // 64 KB
    __shared__ __align__(16) ushort_t sB[2][256 * BK2];  // 64 KB

    const ushort_t* A  = (const ushort_t*)Ab;
    const ushort_t* Bt = (const ushort_t*)Btb;

    f32x4 acc[8][4];
    #pragma unroll
    for (int i = 0; i < 8; ++i)
        #pragma unroll
        for (int j = 0; j < 4; ++j)
            #pragma unroll
            for (int r = 0; r < 4; ++r) acc[i][j][r] = 0.0f;

    // staging: wave w covers tile rows [w*32, w*32+32), 4 issues of 8 rows each.
    // lane l -> row +(l>>3), LDS chunk l&7; source logical chunk (l&7)^(l>>3)
    // so LDS[row][pc] holds logical chunk pc^(row&7).
    const int l8  = lane >> 3;
    const int sch = (lane & 7) ^ l8;
    const ushort_t* gA = A  + (size_t)(m0 + wave * 32 + l8) * K + sch * 8;
    const ushort_t* gB = Bt + (size_t)(n0 + wave * 32 + l8) * K + sch * 8;
    const int ldsb = wave * 32 * BK2;

#define STAGE(s, k0) do { \
    _Pragma("unroll") \
    for (int g = 0; g < 4; ++g) { \
        async16(gA + (size_t)g * 8 * K + (k0), &sA[s][ldsb + g * 8 * BK2]); \
        async16(gB + (size_t)g * 8 * K + (k0), &sB[s][ldsb + g * 8 * BK2]); \
    } } while (0)

    // fragment reads: row_a&7 == lr&7, so physical chunk = (ks*4+quad)^(lr&7)
    const int pc0 = ((quad       ^ (lr & 7)) << 3);
    const int pc1 = (((quad + 4) ^ (lr & 7)) << 3);
    const int arow = (wm * 128 + lr) * BK2;
    const int brow = (wn * 64  + lr) * BK2;

    bf16x8 af[4][2], bfr[2][2];
#define LDA(s, mh) do { \
    _Pragma("unroll") for (int i = 0; i < 4; ++i) { \
        af[i][0] = *(const bf16x8*)&sA[s][arow + ((mh) * 64 + i * 16) * BK2 + pc0]; \
        af[i][1] = *(const bf16x8*)&sA[s][arow + ((mh) * 64 + i * 16) * BK2 + pc1]; \
    } } while (0)
#define LDB(s, nh) do { \
    _Pragma("unroll") for (int j = 0; j < 2; ++j) { \
        bfr[j][0] = *(const bf16x8*)&sB[s][brow + ((nh) * 32 + j * 16) * BK2 + pc0]; \
        bfr[j][1] = *(const bf16x8*)&sB[s][brow + ((nh) * 32 + j * 16) * BK2 + pc1]; \
    } } while (0)
#define MFMA16(mh, nh) do { \
    __builtin_amdgcn_s_setprio(1); \
    _Pragma("unroll") for (int i = 0; i < 4; ++i) \
    _Pragma("unroll") for (int j = 0; j < 2; ++j) { \
        acc[(mh)*4+i][(nh)*2+j] = __builtin_amdgcn_mfma_f32_16x16x32_bf16(af[i][0], bfr[j][0], acc[(mh)*4+i][(nh)*2+j], 0, 0, 0); \
        acc[(mh)*4+i][(nh)*2+j] = __builtin_amdgcn_mfma_f32_16x16x32_bf16(af[i][1], bfr[j][1], acc[(mh)*4+i][(nh)*2+j], 0, 0, 0); \
    } \
    __builtin_amdgcn_s_setprio(0); } while (0)

    // prologue: tile 0 -> slot 0 (one-time full drain)
    STAGE(0, 0);
    WAIT_VM0();
    BARX();

    for (int it = 0; it < 8; ++it) {
        const int k1 = it * 128 + 64;    // tile 2it+1
        const int k2 = it * 128 + 128;   // tile 2it+2
        // ph1: slot0 (0,0) + stage tile 2it+1 -> slot1
        LDA(0, 0); LDB(0, 0);
        STAGE(1, k1);
        BARX(); WAIT_LGKM0();
        MFMA16(0, 0);
        BARX();
        // ph2: (0,1)  [A mh0 cached]
        LDB(0, 1);
        BARX(); WAIT_LGKM0();
        MFMA16(0, 1);
        BARX();
        // ph3: (1,1)  [B nh1 cached]
        LDA(0, 1);
        BARX(); WAIT_LGKM0();
        MFMA16(1, 1);
        BARX();
        // ph4: (1,0)  [A mh1 cached]
        LDB(0, 0);
        BARX(); WAIT_LGKM0();
        MFMA16(1, 0);
        WAIT_VM0();   // tile 2it+1 landed (loads 3 phases old)
        BARX();
        // ph5: slot1 (0,0) + stage tile 2it+2 -> slot0
        LDA(1, 0); LDB(1, 0);
        if (it < 7) STAGE(0, k2);
        BARX(); WAIT_LGKM0();
        MFMA16(0, 0);
        BARX();
        // ph6: (0,1)
        LDB(1, 1);
        BARX(); WAIT_LGKM0();
        MFMA16(0, 1);
        BARX();
        // ph7: (1,1)
        LDA(1, 1);
        BARX(); WAIT_LGKM0();
        MFMA16(1, 1);
        BARX();
        // ph8: (1,0)
        LDB(1, 0);
        BARX(); WAIT_LGKM0();
        MFMA16(1, 0);
        WAIT_VM0();   // tile 2it+2 landed
        BARX();
    }

    // epilogue: C/D layout col=lane&15, row=quad*4+reg
    #pragma unroll
    for (int mf = 0; mf < 8; ++mf) {
        int row = m0 + wm * 128 + mf * 16 + quad * 4;
        #pragma unroll
        for (int nf = 0; nf < 4; ++nf) {
            int col = n0 + wn * 64 + nf * 16 + lr;
            if constexpr (EPI == 0) {
                float bs = b_in[col] * Bv[col];
                #pragma unroll
                for (int r = 0; r < 4; ++r)
                    out_bf[(size_t)(row + r) * N + col] = __float2bfloat16(acc[mf][nf][r] + bs);
            } else {
                float dv = Dvec[col];
                #pragma unroll
                for (int r = 0; r < 4; ++r) {
                    float xv = bf2f(((const ushort_t*)xres_bf)[(size_t)(row + r) * N + col]);
                    out_f[(size_t)(row + r) * N + col] = acc[mf][nf][r] + xv * dv;
                }
            }
        }
    }
#undef STAGE
#undef LDA
#undef LDB
#undef MFMA16
}

// ---- chunked scan: h_t = a*h_{t-1} + b_t, bf16 in/out ----
// v2 (verified round 4, ~34us total saved with prep v2): 4 channels/thread via
// ushort4 (8 B/lane loads, G13), grid (T/32, 8) = 512 blocks, 2/CU.
#define SCH 32
__global__ void scan_kernel(const __hip_bfloat16* __restrict__ b, __hip_bfloat16* __restrict__ h,
                            const float* __restrict__ logA, int T, int DD) {
    int c0 = threadIdx.x * 4;          // 4 channels per thread
    int q  = blockIdx.x;               // chunk index
    int bb = blockIdx.y;               // batch
    float4 la = *(const float4*)(logA + c0);
    float a1c[4], a2c[4], a3c[4], a4c[4];
    a1c[0] = -__expf(la.x); a1c[1] = -__expf(la.y);
    a1c[2] = -__expf(la.z); a1c[3] = -__expf(la.w);
    #pragma unroll
    for (int c = 0; c < 4; ++c) {
        a2c[c] = a1c[c] * a1c[c];
        a3c[c] = a2c[c] * a1c[c];
        a4c[c] = a2c[c] * a2c[c];
    }
    int ts = q * SCH;
    size_t base = (size_t)bb * T * DD + c0;
    float hh[4] = {0.f, 0.f, 0.f, 0.f};
    if (ts > 0) {
        const ushort_t* wp = (const ushort_t*)b + base + (size_t)(ts - 32) * DD;
        #pragma unroll
        for (int t = 0; t < 32; t += 4) {
            ushort4 v0 = *(const ushort4*)(wp);
            ushort4 v1 = *(const ushort4*)(wp + DD);
            ushort4 v2 = *(const ushort4*)(wp + 2 * (size_t)DD);
            ushort4 v3 = *(const ushort4*)(wp + 3 * (size_t)DD);
            wp += 4 * (size_t)DD;
            const ushort_t* p0 = (const ushort_t*)&v0;
            const ushort_t* p1 = (const ushort_t*)&v1;
            const ushort_t* p2 = (const ushort_t*)&v2;
            const ushort_t* p3 = (const ushort_t*)&v3;
            #pragma unroll
            for (int c = 0; c < 4; ++c) {
                float s = fmaf(a3c[c], bf2f(p0[c]), fmaf(a2c[c], bf2f(p1[c]),
                          fmaf(a1c[c], bf2f(p2[c]), bf2f(p3[c]))));
                hh[c] = fmaf(a4c[c], hh[c], s);
            }
        }
    }
    const ushort_t* bp = (const ushort_t*)b + base + (size_t)ts * DD;
    ushort_t* hp = (ushort_t*)h + base + (size_t)ts * DD;
    #pragma unroll
    for (int t = 0; t < SCH; t += 4) {
        ushort4 v0 = *(const ushort4*)(bp);
        ushort4 v1 = *(const ushort4*)(bp + DD);
        ushort4 v2 = *(const ushort4*)(bp + 2 * (size_t)DD);
        ushort4 v3 = *(const ushort4*)(bp + 3 * (size_t)DD);
        bp += 4 * (size_t)DD;
        const ushort_t* p0 = (const ushort_t*)&v0;
        const ushort_t* p1 = (const ushort_t*)&v1;
        const ushort_t* p2 = (const ushort_t*)&v2;
        const ushort_t* p3 = (const ushort_t*)&v3;
        ushort4 o0, o1, o2, o3;
        ushort_t* q0 = (ushort_t*)&o0; ushort_t* q1 = (ushort_t*)&o1;
        ushort_t* q2 = (ushort_t*)&o2; ushort_t* q3 = (ushort_t*)&o3;
        #pragma unroll
        for (int c = 0; c < 4; ++c) {
            hh[c] = fmaf(a1c[c], hh[c], bf2f(p0[c])); q0[c] = f2bf(hh[c]);
            hh[c] = fmaf(a1c[c], hh[c], bf2f(p1[c])); q1[c] = f2bf(hh[c]);
            hh[c] = fmaf(a1c[c], hh[c], bf2f(p2[c])); q2[c] = f2bf(hh[c]);
            hh[c] = fmaf(a1c[c], hh[c], bf2f(p3[c])); q3[c] = f2bf(hh[c]);
        }
        *(ushort4*)hp = o0;
        *(ushort4*)(hp + DD) = o1;
        *(ushort4*)(hp + 2 * (size_t)DD) = o2;
        *(ushort4*)(hp + 3 * (size_t)DD) = o3;
        hp += 4 * (size_t)DD;
    }
}

extern "C" void kernel_launch(void* const* d_in, const int* in_sizes, int n_in,
                              void* d_out, int out_size, void* d_ws, size_t ws_size,
                              hipStream_t stream) {
    const float* x    = (const float*)d_in[0];
    const float* W_in = (const float*)d_in[1];
    const float* b_in = (const float*)d_in[2];
    const float* logA = (const float*)d_in[3];
    const float* Bv   = (const float*)d_in[4];
    const float* C    = (const float*)d_in[5];
    const float* Dv   = (const float*)d_in[6];
    float* out = (float*)d_out;

    const int Bsz = 8, T = 2048, d = 1024;
    const int M = Bsz * T;  // 16384

    // workspace carve (~100 MB)
    char* w = (char*)d_ws;
    __hip_bfloat16* xb   = (__hip_bfloat16*)w;                 // 32 MB
    __hip_bfloat16* Wpt  = xb + (size_t)M * d;                 //  2 MB
    __hip_bfloat16* Ct   = Wpt + (size_t)d * d;                //  2 MB
    __hip_bfloat16* bbuf = Ct + (size_t)d * d;                 // 32 MB
    __hip_bfloat16* hbuf = bbuf + (size_t)M * d;               // 32 MB

    prep_fused<<<8192 + 2048, 256, 0, stream>>>(x, W_in, C, Bv, xb, Wpt, Ct);

    gemm256<0><<<256, 512, 0, stream>>>(xb, Wpt, b_in, Bv, bbuf, nullptr, nullptr, nullptr);
    scan_kernel<<<dim3(T / SCH, Bsz), 256, 0, stream>>>(bbuf, hbuf, logA, T, d);
    gemm256<1><<<256, 512, 0, stream>>>(hbuf, Ct, nullptr, nullptr, nullptr, xb, Dv, out);
}

// Round 6
// 225.899 us; speedup vs baseline: 1.0578x; 1.0372x over previous
//
#include <hip/hip_runtime.h>
#include <hip/hip_bf16.h>

typedef unsigned short ushort_t;
typedef __bf16 bf16x8 __attribute__((ext_vector_type(8)));
typedef float f32x4 __attribute__((ext_vector_type(4)));
typedef ushort_t ushort8_t __attribute__((ext_vector_type(8)));

__device__ __forceinline__ float bf2f(ushort_t u) {
    union { unsigned int i; float f; } x; x.i = ((unsigned int)u) << 16; return x.f;
}
__device__ __forceinline__ ushort_t f2bf(float f) {
    __hip_bfloat16 h = __float2bfloat16(f);
    return *(ushort_t*)&h;
}
__device__ __forceinline__ void async16(const void* g, void* l) {
    __builtin_amdgcn_global_load_lds((const __attribute__((address_space(1))) void*)g,
                                     (__attribute__((address_space(3))) void*)l, 16, 0, 0);
}

// ---- fused prep: blocks [0,8192): x fp32->bf16 (2 float4/thread); [8192,9216): W_in^T*Bv; [9216,10240): C^T ----
__global__ void prep_fused(const float* __restrict__ x, const float* __restrict__ W_in,
                           const float* __restrict__ C, const float* __restrict__ Bv,
                           __hip_bfloat16* __restrict__ xb, __hip_bfloat16* __restrict__ Wpt,
                           __hip_bfloat16* __restrict__ Ct) {
    int bid = blockIdx.x;
    if (bid < 8192) {
        size_t idx = ((size_t)bid * 256 + threadIdx.x) * 8;
        float4 v0 = *(const float4*)(x + idx);
        float4 v1 = *(const float4*)(x + idx + 4);
        ushort8_t ov;
        ov[0] = f2bf(v0.x); ov[1] = f2bf(v0.y); ov[2] = f2bf(v0.z); ov[3] = f2bf(v0.w);
        ov[4] = f2bf(v1.x); ov[5] = f2bf(v1.y); ov[6] = f2bf(v1.z); ov[7] = f2bf(v1.w);
        *(ushort8_t*)((ushort_t*)xb + idx) = ov;
        return;
    }
    __shared__ float tile[32][33];
    const float* in;
    __hip_bfloat16* out;
    bool do_scale;
    int lid;
    if (bid < 9216) { lid = bid - 8192; in = W_in; out = Wpt; do_scale = true; }
    else            { lid = bid - 9216; in = C;    out = Ct;  do_scale = false; }
    int bx = (lid & 31) * 32;   // n base
    int by = (lid >> 5) * 32;   // k base
    int tx = threadIdx.x & 31, ty = threadIdx.x >> 5;  // ty 0..7
    #pragma unroll
    for (int i = 0; i < 32; i += 8)
        tile[ty + i][tx] = in[(size_t)(by + ty + i) * 1024 + bx + tx];
    __syncthreads();
    #pragma unroll
    for (int i = 0; i < 32; i += 8) {
        int n = bx + ty + i;
        int k = by + tx;
        float s = do_scale ? Bv[n] : 1.0f;
        out[(size_t)n * 1024 + k] = __float2bfloat16(tile[tx][ty + i] * s);
    }
}

// ---- 256x256 GEMM, 2-barrier-per-iter loose schedule: D = A * Bt^T ----
// M=16384, N=1024, K=1024. 512 thr = 8 waves (2M x 4N), per-wave C = 128x64.
// Evolution: r3 8-phase lockstep (2 barriers/phase) = 53.5us, MfmaUtil 24%.
// Cycle model: 128 phases x (~620cy MFMA + ~400cy serialized ds_read+barrier
// skew) = 134k cy — the per-phase barriers serialize ds_read vs MFMA with only
// 2 waves/SIMD. This rev keeps ONLY the 2 structurally-required barriers/iter
// (slot-overwrite boundaries, after hard lgkm0+vm0 drain). Plain-C LDS reads:
// compiler inserts counted lgkm waits and pipelines reads under MFMAs.
// Correctness: slot readers drain (lgkm0) before half-end barrier; STAGE of that
// slot issues only after it; staged-data-ready = own-wave vm0 drain + barrier.
// NOTE (r4/r5 errata): global_load_lds is vmcnt-only (global_, not flat_) —
// r3's ph1 lgkmcnt(0) after STAGE proves it. r4's regression was stage-issue
// BEFORE ds_reads under lockstep, not an lgkm interaction.
#define CBAR() asm volatile("" ::: "memory")
#define BARX() do { CBAR(); __builtin_amdgcn_s_barrier(); CBAR(); } while (0)
#define WAIT_LGKM0() do { asm volatile("s_waitcnt lgkmcnt(0)" ::: "memory"); \
                          __builtin_amdgcn_sched_barrier(0); } while (0)
#define WAIT_VM0() asm volatile("s_waitcnt vmcnt(0)" ::: "memory")

template <int EPI>
__global__ __launch_bounds__(512) void gemm256(
    const __hip_bfloat16* __restrict__ Ab, const __hip_bfloat16* __restrict__ Btb,
    const float* __restrict__ b_in, const float* __restrict__ Bv,
    __hip_bfloat16* __restrict__ out_bf,
    const __hip_bfloat16* __restrict__ xres_bf, const float* __restrict__ Dvec,
    float* __restrict__ out_f) {
    constexpr int N = 1024, K = 1024;
    constexpr int BK2 = 64;
    const int tid  = threadIdx.x;
    const int wave = tid >> 6;     // 0..7
    const int lane = tid & 63;
    const int quad = lane >> 4;    // 0..3
    const int lr   = lane & 15;
    const int wm   = wave >> 2;    // 0..1
    const int wn   = wave & 3;     // 0..3

    // bijective XCD swizzle: 256 wgs, 32/XCD
    const int lin   = blockIdx.x;
    const int wg    = (lin & 7) * 32 + (lin >> 3);
    const int m0    = (wg >> 2) * 256;
    const int n0    = (wg & 3) * 256;

    __shared__ __align__(16) ushort_t sA[2][256 * BK2];  // 64 KB
    __shared__ __align__(16) ushort_t sB[2][256 * BK2];  // 64 KB

    const ushort_t* A  = (const ushort_t*)Ab;
    const ushort_t* Bt = (const ushort_t*)Btb;

    f32x4 acc[8][4];
    #pragma unroll
    for (int i = 0; i < 8; ++i)
        #pragma unroll
        for (int j = 0; j < 4; ++j)
            #pragma unroll
            for (int r = 0; r < 4; ++r) acc[i][j][r] = 0.0f;

    // staging: wave w covers tile rows [w*32, w*32+32), 4 issues of 8 rows each.
    // lane l -> row +(l>>3), LDS chunk l&7; source logical chunk (l&7)^(l>>3)
    // so LDS[row][pc] holds logical chunk pc^(row&7).
    const int l8  = lane >> 3;
    const int sch = (lane & 7) ^ l8;
    const ushort_t* gA = A  + (size_t)(m0 + wave * 32 + l8) * K + sch * 8;
    const ushort_t* gB = Bt + (size_t)(n0 + wave * 32 + l8) * K + sch * 8;
    const int ldsb = wave * 32 * BK2;

#define STAGE(s, k0) do { \
    _Pragma("unroll") \
    for (int g = 0; g < 4; ++g) { \
        async16(gA + (size_t)g * 8 * K + (k0), &sA[s][ldsb + g * 8 * BK2]); \
        async16(gB + (size_t)g * 8 * K + (k0), &sB[s][ldsb + g * 8 * BK2]); \
    } } while (0)

    // fragment reads: row_a&7 == lr&7, so physical chunk = (ks*4+quad)^(lr&7)
    const int pc0 = ((quad       ^ (lr & 7)) << 3);
    const int pc1 = (((quad + 4) ^ (lr & 7)) << 3);
    const int arow = (wm * 128 + lr) * BK2;
    const int brow = (wn * 64  + lr) * BK2;

    bf16x8 af[4][2], bfr[2][2];
#define LDA(s, mh) do { \
    _Pragma("unroll") for (int i = 0; i < 4; ++i) { \
        af[i][0] = *(const bf16x8*)&sA[s][arow + ((mh) * 64 + i * 16) * BK2 + pc0]; \
        af[i][1] = *(const bf16x8*)&sA[s][arow + ((mh) * 64 + i * 16) * BK2 + pc1]; \
    } } while (0)
#define LDB(s, nh) do { \
    _Pragma("unroll") for (int j = 0; j < 2; ++j) { \
        bfr[j][0] = *(const bf16x8*)&sB[s][brow + ((nh) * 32 + j * 16) * BK2 + pc0]; \
        bfr[j][1] = *(const bf16x8*)&sB[s][brow + ((nh) * 32 + j * 16) * BK2 + pc1]; \
    } } while (0)
#define MFMA16(mh, nh) do { \
    __builtin_amdgcn_s_setprio(1); \
    _Pragma("unroll") for (int i = 0; i < 4; ++i) \
    _Pragma("unroll") for (int j = 0; j < 2; ++j) { \
        acc[(mh)*4+i][(nh)*2+j] = __builtin_amdgcn_mfma_f32_16x16x32_bf16(af[i][0], bfr[j][0], acc[(mh)*4+i][(nh)*2+j], 0, 0, 0); \
        acc[(mh)*4+i][(nh)*2+j] = __builtin_amdgcn_mfma_f32_16x16x32_bf16(af[i][1], bfr[j][1], acc[(mh)*4+i][(nh)*2+j], 0, 0, 0); \
    } \
    __builtin_amdgcn_s_setprio(0); } while (0)

    // prologue: tile 0 -> slot 0 (one-time full drain)
    STAGE(0, 0);
    WAIT_VM0();
    BARX();

    for (int it = 0; it < 8; ++it) {
        const int k1 = it * 128 + 64;    // tile 2it+1
        const int k2 = it * 128 + 128;   // tile 2it+2
        // HALF A: compute slot0 (tile 2it), stage tile 2it+1 -> slot1.
        // ds_reads issued first (r4 lesson), STAGE after (still post-barrier).
        LDA(0, 0); LDB(0, 0);
        STAGE(1, k1);
        MFMA16(0, 0);
        LDB(0, 1);
        MFMA16(0, 1);
        LDA(0, 1);
        MFMA16(1, 1);
        LDB(0, 0);
        MFMA16(1, 0);
        WAIT_LGKM0();   // all slot-0 reads complete before slot-0 overwrite next half
        WAIT_VM0();     // tile 2it+1 landed (issued ~3 MFMA-clusters ago)
        BARX();
        // HALF B: compute slot1 (tile 2it+1), stage tile 2it+2 -> slot0.
        LDA(1, 0); LDB(1, 0);
        if (it < 7) STAGE(0, k2);
        MFMA16(0, 0);
        LDB(1, 1);
        MFMA16(0, 1);
        LDA(1, 1);
        MFMA16(1, 1);
        LDB(1, 0);
        MFMA16(1, 0);
        WAIT_LGKM0();
        WAIT_VM0();     // tile 2it+2 landed
        BARX();
    }

    // epilogue: C/D layout col=lane&15, row=quad*4+reg
    #pragma unroll
    for (int mf = 0; mf < 8; ++mf) {
        int row = m0 + wm * 128 + mf * 16 + quad * 4;
        #pragma unroll
        for (int nf = 0; nf < 4; ++nf) {
            int col = n0 + wn * 64 + nf * 16 + lr;
            if constexpr (EPI == 0) {
                float bs = b_in[col] * Bv[col];
                #pragma unroll
                for (int r = 0; r < 4; ++r)
                    out_bf[(size_t)(row + r) * N + col] = __float2bfloat16(acc[mf][nf][r] + bs);
            } else {
                float dv = Dvec[col];
                #pragma unroll
                for (int r = 0; r < 4; ++r) {
                    float xv = bf2f(((const ushort_t*)xres_bf)[(size_t)(row + r) * N + col]);
                    out_f[(size_t)(row + r) * N + col] = acc[mf][nf][r] + xv * dv;
                }
            }
        }
    }
#undef STAGE
#undef LDA
#undef LDB
#undef MFMA16
}

// ---- chunked scan: h_t = a*h_{t-1} + b_t, bf16 in/out ----
// v2: 4 channels/thread via ushort4 (8 B/lane loads, G13), grid (T/32, 8).
#define SCH 32
__global__ void scan_kernel(const __hip_bfloat16* __restrict__ b, __hip_bfloat16* __restrict__ h,
                            const float* __restrict__ logA, int T, int DD) {
    int c0 = threadIdx.x * 4;          // 4 channels per thread
    int q  = blockIdx.x;               // chunk index
    int bb = blockIdx.y;               // batch
    float4 la = *(const float4*)(logA + c0);
    float a1c[4], a2c[4], a3c[4], a4c[4];
    a1c[0] = -__expf(la.x); a1c[1] = -__expf(la.y);
    a1c[2] = -__expf(la.z); a1c[3] = -__expf(la.w);
    #pragma unroll
    for (int c = 0; c < 4; ++c) {
        a2c[c] = a1c[c] * a1c[c];
        a3c[c] = a2c[c] * a1c[c];
        a4c[c] = a2c[c] * a2c[c];
    }
    int ts = q * SCH;
    size_t base = (size_t)bb * T * DD + c0;
    float hh[4] = {0.f, 0.f, 0.f, 0.f};
    if (ts > 0) {
        const ushort_t* wp = (const ushort_t*)b + base + (size_t)(ts - 32) * DD;
        #pragma unroll
        for (int t = 0; t < 32; t += 4) {
            ushort4 v0 = *(const ushort4*)(wp);
            ushort4 v1 = *(const ushort4*)(wp + DD);
            ushort4 v2 = *(const ushort4*)(wp + 2 * (size_t)DD);
            ushort4 v3 = *(const ushort4*)(wp + 3 * (size_t)DD);
            wp += 4 * (size_t)DD;
            const ushort_t* p0 = (const ushort_t*)&v0;
            const ushort_t* p1 = (const ushort_t*)&v1;
            const ushort_t* p2 = (const ushort_t*)&v2;
            const ushort_t* p3 = (const ushort_t*)&v3;
            #pragma unroll
            for (int c = 0; c < 4; ++c) {
                float s = fmaf(a3c[c], bf2f(p0[c]), fmaf(a2c[c], bf2f(p1[c]),
                          fmaf(a1c[c], bf2f(p2[c]), bf2f(p3[c]))));
                hh[c] = fmaf(a4c[c], hh[c], s);
            }
        }
    }
    const ushort_t* bp = (const ushort_t*)b + base + (size_t)ts * DD;
    ushort_t* hp = (ushort_t*)h + base + (size_t)ts * DD;
    #pragma unroll
    for (int t = 0; t < SCH; t += 4) {
        ushort4 v0 = *(const ushort4*)(bp);
        ushort4 v1 = *(const ushort4*)(bp + DD);
        ushort4 v2 = *(const ushort4*)(bp + 2 * (size_t)DD);
        ushort4 v3 = *(const ushort4*)(bp + 3 * (size_t)DD);
        bp += 4 * (size_t)DD;
        const ushort_t* p0 = (const ushort_t*)&v0;
        const ushort_t* p1 = (const ushort_t*)&v1;
        const ushort_t* p2 = (const ushort_t*)&v2;
        const ushort_t* p3 = (const ushort_t*)&v3;
        ushort4 o0, o1, o2, o3;
        ushort_t* q0 = (ushort_t*)&o0; ushort_t* q1 = (ushort_t*)&o1;
        ushort_t* q2 = (ushort_t*)&o2; ushort_t* q3 = (ushort_t*)&o3;
        #pragma unroll
        for (int c = 0; c < 4; ++c) {
            hh[c] = fmaf(a1c[c], hh[c], bf2f(p0[c])); q0[c] = f2bf(hh[c]);
            hh[c] = fmaf(a1c[c], hh[c], bf2f(p1[c])); q1[c] = f2bf(hh[c]);
            hh[c] = fmaf(a1c[c], hh[c], bf2f(p2[c])); q2[c] = f2bf(hh[c]);
            hh[c] = fmaf(a1c[c], hh[c], bf2f(p3[c])); q3[c] = f2bf(hh[c]);
        }
        *(ushort4*)hp = o0;
        *(ushort4*)(hp + DD) = o1;
        *(ushort4*)(hp + 2 * (size_t)DD) = o2;
        *(ushort4*)(hp + 3 * (size_t)DD) = o3;
        hp += 4 * (size_t)DD;
    }
}

extern "C" void kernel_launch(void* const* d_in, const int* in_sizes, int n_in,
                              void* d_out, int out_size, void* d_ws, size_t ws_size,
                              hipStream_t stream) {
    const float* x    = (const float*)d_in[0];
    const float* W_in = (const float*)d_in[1];
    const float* b_in = (const float*)d_in[2];
    const float* logA = (const float*)d_in[3];
    const float* Bv   = (const float*)d_in[4];
    const float* C    = (const float*)d_in[5];
    const float* Dv   = (const float*)d_in[6];
    float* out = (float*)d_out;

    const int Bsz = 8, T = 2048, d = 1024;
    const int M = Bsz * T;  // 16384

    // workspace carve (~100 MB)
    char* w = (char*)d_ws;
    __hip_bfloat16* xb   = (__hip_bfloat16*)w;                 // 32 MB
    __hip_bfloat16* Wpt  = xb + (size_t)M * d;                 //  2 MB
    __hip_bfloat16* Ct   = Wpt + (size_t)d * d;                //  2 MB
    __hip_bfloat16* bbuf = Ct + (size_t)d * d;                 // 32 MB
    __hip_bfloat16* hbuf = bbuf + (size_t)M * d;               // 32 MB

    prep_fused<<<8192 + 2048, 256, 0, stream>>>(x, W_in, C, Bv, xb, Wpt, Ct);

    gemm256<0><<<256, 512, 0, stream>>>(xb, Wpt, b_in, Bv, bbuf, nullptr, nullptr, nullptr);
    scan_kernel<<<dim3(T / SCH, Bsz), 256, 0, stream>>>(bbuf, hbuf, logA, T, d);
    gemm256<1><<<256, 512, 0, stream>>>(hbuf, Ct, nullptr, nullptr, nullptr, xb, Dv, out);
}